// Round 4
// baseline (108.383 us; speedup 1.0000x reference)
//
#include <hip/hip_runtime.h>
#include <math.h>

#define BINS 10
#define IGNORE_INDEX (-100)
#define NSHADOW 64      // shadow histograms to spread atomic contention
#define SH_STRIDE 16    // padded bin stride per shadow

typedef float fvec4 __attribute__((ext_vector_type(4)));

__device__ __forceinline__ float safe_expf(float d) {
    // d may be NaN (-inf - -inf) or -inf; both mean "scale by 0"
    return (d != d || d == -INFINITY) ? 0.0f : __expf(d);
}

__device__ __forceinline__ void acc4(fvec4 v, float& m, float& s) {
    float vm = fmaxf(fmaxf(v.x, v.y), fmaxf(v.z, v.w));
    if (vm > m) { s *= safe_expf(m - vm); m = vm; }
    s += (__expf(v.x - m) + __expf(v.y - m)) + (__expf(v.z - m) + __expf(v.w - m));
}

// One block per row: online logsumexp over C columns, then per-row stats
// pushed straight into shadow histograms (no per-row arrays).
__global__ __launch_bounds__(256) void ghmc_row_kernel(
    const float* __restrict__ y_pred,
    const int*   __restrict__ y_true,
    int*         __restrict__ counts_sh,   // [NSHADOW][SH_STRIDE]
    float*       __restrict__ binsum_sh,   // [NSHADOW][SH_STRIDE]
    int*         __restrict__ nl_sh,       // [NSHADOW]
    int C)
{
    const int row = blockIdx.x;
    const float* rp = y_pred + (size_t)row * (size_t)C;
    const int tid = threadIdx.x;
    const int nthreads = blockDim.x;   // 256

    // Prefetch label + true-class logit early; latency hides under streaming.
    const int label = y_true[row];
    const int cidx  = label < 0 ? 0 : (label >= C ? C - 1 : label);
    const float xt  = rp[cidx];

    float m0 = -INFINITY, s0 = 0.0f;
    float m1 = -INFINITY, s1 = 0.0f;
    float m2 = -INFINITY, s2 = 0.0f;
    float m3 = -INFINITY, s3 = 0.0f;

    const int n4 = C >> 2;
    const fvec4* rp4 = reinterpret_cast<const fvec4*>(rp);

    int i = tid;
    // 4-way unrolled: four independent accumulator pairs -> 4 loads in flight.
    for (; i + 3 * nthreads < n4; i += 4 * nthreads) {
        fvec4 a = __builtin_nontemporal_load(&rp4[i]);
        fvec4 b = __builtin_nontemporal_load(&rp4[i + nthreads]);
        fvec4 c = __builtin_nontemporal_load(&rp4[i + 2 * nthreads]);
        fvec4 d = __builtin_nontemporal_load(&rp4[i + 3 * nthreads]);
        acc4(a, m0, s0);
        acc4(b, m1, s1);
        acc4(c, m2, s2);
        acc4(d, m3, s3);
    }
    for (; i < n4; i += nthreads) {
        fvec4 a = __builtin_nontemporal_load(&rp4[i]);
        acc4(a, m0, s0);
    }
    // scalar tail if C % 4 != 0
    for (int j = (n4 << 2) + tid; j < C; j += nthreads) {
        float v = rp[j];
        if (v > m0) { s0 *= safe_expf(m0 - v); m0 = v; }
        s0 += __expf(v - m0);
    }

    // merge the four accumulators
    {
        float nm = fmaxf(m0, m1);
        s0 = s0 * safe_expf(m0 - nm) + s1 * safe_expf(m1 - nm);
        m0 = nm;
        nm = fmaxf(m2, m3);
        s2 = s2 * safe_expf(m2 - nm) + s3 * safe_expf(m3 - nm);
        m2 = nm;
        nm = fmaxf(m0, m2);
        s0 = s0 * safe_expf(m0 - nm) + s2 * safe_expf(m2 - nm);
        m0 = nm;
    }

    // wave-64 butterfly combine of (m, s)
    #pragma unroll
    for (int off = 32; off >= 1; off >>= 1) {
        float om = __shfl_xor(m0, off);
        float os = __shfl_xor(s0, off);
        float nm = fmaxf(m0, om);
        s0 = s0 * safe_expf(m0 - nm) + os * safe_expf(om - nm);
        m0 = nm;
    }

    __shared__ float sm[4], ss[4];
    const int wave = tid >> 6, lane = tid & 63;
    if (lane == 0) { sm[wave] = m0; ss[wave] = s0; }
    __syncthreads();

    if (tid == 0) {
        float M = sm[0], S = ss[0];
        #pragma unroll
        for (int w = 1; w < 4; ++w) {
            float om = sm[w], os = ss[w];
            float nm = fmaxf(M, om);
            S = S * safe_expf(M - nm) + os * safe_expf(om - nm);
            M = nm;
        }
        float lp = xt - M - logf(S);

        float p = __expf(lp);
        float g = 1.0f - p;

        // searchsorted(edges, g, side='right') - 1, edges[k] = k/10 in fp32
        int bin = -1;
        #pragma unroll
        for (int k = 0; k <= BINS; ++k) {
            float edge = (float)k / (float)BINS;
            if (edge <= g) bin = k;
        }
        const bool valid = (label != IGNORE_INDEX);
        const bool in_range = (bin >= 0) && (bin < BINS) && valid;

        const int sh = row & (NSHADOW - 1);
        if (valid) atomicAdd(&nl_sh[sh], 1);
        if (in_range) {
            atomicAdd(&counts_sh[sh * SH_STRIDE + bin], 1);
            atomicAdd(&binsum_sh[sh * SH_STRIDE + bin], lp);
        }
    }
}

// One wave: reduce shadow histograms, compute weights and final loss.
__global__ __launch_bounds__(64) void ghmc_finalize_kernel(
    const int*   __restrict__ counts_sh,
    const float* __restrict__ binsum_sh,
    const int*   __restrict__ nl_sh,
    float*       __restrict__ out)
{
    const int lane = threadIdx.x;

    __shared__ int   s_counts[BINS];
    __shared__ float s_binsum[BINS];
    __shared__ int   s_nl;

    if (lane < BINS) {
        int c = 0;
        float bs = 0.0f;
        #pragma unroll 4
        for (int s = 0; s < NSHADOW; ++s) {
            c  += counts_sh[s * SH_STRIDE + lane];
            bs += binsum_sh[s * SH_STRIDE + lane];
        }
        s_counts[lane] = c;
        s_binsum[lane] = bs;
    }
    if (lane == 63) {
        int nl = 0;
        #pragma unroll 4
        for (int s = 0; s < NSHADOW; ++s) nl += nl_sh[s];
        s_nl = nl;
    }
    __syncthreads();

    if (lane == 0) {
        const float num_labels = (float)s_nl;
        int n = 0;
        #pragma unroll
        for (int k = 0; k < BINS; ++k) n += (s_counts[k] > 0) ? 1 : 0;
        const float nf = fmaxf((float)n, 1.0f);
        float total = 0.0f;
        #pragma unroll
        for (int k = 0; k < BINS; ++k) {
            float w = (s_counts[k] > 0) ? (num_labels / (float)s_counts[k]) : 0.0f;
            w /= nf;
            total += w * s_binsum[k];
        }
        out[0] = -total / num_labels;
    }
}

extern "C" void kernel_launch(void* const* d_in, const int* in_sizes, int n_in,
                              void* d_out, int out_size, void* d_ws, size_t ws_size,
                              hipStream_t stream) {
    const float* y_pred = (const float*)d_in[0];
    const int*   y_true = (const int*)d_in[1];
    const int B = in_sizes[1];
    const int C = (int)(in_sizes[0] / (size_t)in_sizes[1]);
    float* out = (float*)d_out;

    char* ws = (char*)d_ws;
    int*   counts_sh = (int*)ws;                                   // 64*16 ints
    float* binsum_sh = (float*)(ws + NSHADOW * SH_STRIDE * 4);     // 64*16 floats
    int*   nl_sh     = (int*)(ws + 2 * NSHADOW * SH_STRIDE * 4);   // 64 ints
    const size_t stats_bytes = 2 * NSHADOW * SH_STRIDE * 4 + NSHADOW * 4;

    hipMemsetAsync(ws, 0, stats_bytes, stream);
    ghmc_row_kernel<<<B, 256, 0, stream>>>(y_pred, y_true, counts_sh, binsum_sh, nl_sh, C);
    ghmc_finalize_kernel<<<1, 64, 0, stream>>>(counts_sh, binsum_sh, nl_sh, out);
}

// Round 5
// 89.736 us; speedup vs baseline: 1.2078x; 1.2078x over previous
//
#include <hip/hip_runtime.h>
#include <math.h>

#define BINS 10
#define IGNORE_INDEX (-100)

typedef float fvec4 __attribute__((ext_vector_type(4)));
typedef int   ivec4 __attribute__((ext_vector_type(4)));

__device__ __forceinline__ float safe_expf(float d) {
    // d may be NaN (-inf - -inf) or -inf; both mean "scale by 0"
    return (d != d || d == -INFINITY) ? 0.0f : __expf(d);
}

__device__ __forceinline__ void acc4(fvec4 v, float& m, float& s) {
    float vm = fmaxf(fmaxf(v.x, v.y), fmaxf(v.z, v.w));
    if (vm > m) { s *= safe_expf(m - vm); m = vm; }
    s += (__expf(v.x - m) + __expf(v.y - m)) + (__expf(v.z - m) + __expf(v.w - m));
}

// One block per row: online logsumexp over C columns, then per-row stats.
// 2-way unroll: 2 NT loads in flight per lane (4-way measured -20%: R3).
__global__ __launch_bounds__(256) void ghmc_row_kernel(
    const float* __restrict__ y_pred,
    const int*   __restrict__ y_true,
    float*       __restrict__ logprob,
    int*         __restrict__ seg,
    int C)
{
    const int row = blockIdx.x;
    const float* rp = y_pred + (size_t)row * (size_t)C;
    const int tid = threadIdx.x;
    const int nthreads = blockDim.x;   // 256

    // Prefetch label + true-class logit early; latency hides under streaming.
    const int label = y_true[row];
    const int cidx  = label < 0 ? 0 : (label >= C ? C - 1 : label);
    const float xt  = rp[cidx];

    float m0 = -INFINITY, s0 = 0.0f;
    float m1 = -INFINITY, s1 = 0.0f;

    const int n4 = C >> 2;
    const fvec4* rp4 = reinterpret_cast<const fvec4*>(rp);

    int i = tid;
    for (; i + nthreads < n4; i += 2 * nthreads) {
        fvec4 a = __builtin_nontemporal_load(&rp4[i]);
        fvec4 b = __builtin_nontemporal_load(&rp4[i + nthreads]);
        acc4(a, m0, s0);
        acc4(b, m1, s1);
    }
    for (; i < n4; i += nthreads) {
        fvec4 a = __builtin_nontemporal_load(&rp4[i]);
        acc4(a, m0, s0);
    }
    // scalar tail if C % 4 != 0
    for (int j = (n4 << 2) + tid; j < C; j += nthreads) {
        float v = rp[j];
        if (v > m0) { s0 *= safe_expf(m0 - v); m0 = v; }
        s0 += __expf(v - m0);
    }

    // merge the two accumulators
    {
        float nm = fmaxf(m0, m1);
        s0 = s0 * safe_expf(m0 - nm) + s1 * safe_expf(m1 - nm);
        m0 = nm;
    }

    // wave-64 butterfly combine of (m, s)
    #pragma unroll
    for (int off = 32; off >= 1; off >>= 1) {
        float om = __shfl_xor(m0, off);
        float os = __shfl_xor(s0, off);
        float nm = fmaxf(m0, om);
        s0 = s0 * safe_expf(m0 - nm) + os * safe_expf(om - nm);
        m0 = nm;
    }

    __shared__ float sm[4], ss[4];
    const int wave = tid >> 6, lane = tid & 63;
    if (lane == 0) { sm[wave] = m0; ss[wave] = s0; }
    __syncthreads();

    if (tid == 0) {
        float M = sm[0], S = ss[0];
        #pragma unroll
        for (int w = 1; w < 4; ++w) {
            float om = sm[w], os = ss[w];
            float nm = fmaxf(M, om);
            S = S * safe_expf(M - nm) + os * safe_expf(om - nm);
            M = nm;
        }
        float lp = xt - M - logf(S);
        logprob[row] = lp;

        float p = __expf(lp);
        float g = 1.0f - p;

        // searchsorted(edges, g, side='right') - 1, edges[k] = k/10 in fp32
        int bin = -1;
        #pragma unroll
        for (int k = 0; k <= BINS; ++k) {
            float edge = (float)k / (float)BINS;
            if (edge <= g) bin = k;
        }
        const bool valid = (label != IGNORE_INDEX);
        const bool in_range = (bin >= 0) && (bin < BINS) && valid;
        seg[row] = in_range ? bin : BINS;
    }
}

// Single block, 1024 threads: vectorized histogram + weights + loss.
__global__ __launch_bounds__(1024) void ghmc_finalize_kernel(
    const int*   __restrict__ y_true,
    const float* __restrict__ logprob,
    const int*   __restrict__ seg,
    float*       __restrict__ out,
    int B)
{
    const int tid = threadIdx.x;
    const int wave = tid >> 6, lane = tid & 63;
    const int NW = 16;  // 1024 / 64

    __shared__ int s_counts[BINS + 1];
    if (tid < BINS + 1) s_counts[tid] = 0;
    __syncthreads();

    // Pass 1: counts histogram + num_labels (vectorized: 4 elems/thread/iter)
    int nl = 0;
    const int nv = B >> 2;
    const ivec4* yt4 = reinterpret_cast<const ivec4*>(y_true);
    const ivec4* sg4 = reinterpret_cast<const ivec4*>(seg);
    for (int i = tid; i < nv; i += blockDim.x) {
        ivec4 lb = yt4[i];
        ivec4 sg = sg4[i];
        #pragma unroll
        for (int k = 0; k < 4; ++k) {
            nl += (lb[k] != IGNORE_INDEX) ? 1 : 0;
            if (sg[k] < BINS) atomicAdd(&s_counts[sg[k]], 1);
        }
    }
    for (int i = (nv << 2) + tid; i < B; i += blockDim.x) {
        nl += (y_true[i] != IGNORE_INDEX) ? 1 : 0;
        const int s = seg[i];
        if (s < BINS) atomicAdd(&s_counts[s], 1);
    }
    #pragma unroll
    for (int off = 32; off >= 1; off >>= 1) nl += __shfl_xor(nl, off);

    __shared__ int snl[NW];
    if (lane == 0) snl[wave] = nl;
    __syncthreads();

    __shared__ float wpb[BINS + 1];
    __shared__ float s_num_labels;
    if (tid == 0) {
        int NL = 0;
        #pragma unroll
        for (int w = 0; w < NW; ++w) NL += snl[w];
        const float num_labels = (float)NL;
        s_num_labels = num_labels;
        int n = 0;
        #pragma unroll
        for (int k = 0; k < BINS; ++k) n += (s_counts[k] > 0) ? 1 : 0;
        const float nf = fmaxf((float)n, 1.0f);
        #pragma unroll
        for (int k = 0; k < BINS; ++k) {
            float w = (s_counts[k] > 0) ? (num_labels / (float)s_counts[k]) : 0.0f;
            wpb[k] = w / nf;
        }
        wpb[BINS] = 0.0f;  // overflow bin weight 0
    }
    __syncthreads();

    // Pass 2: weighted sum (vectorized)
    float acc = 0.0f;
    const fvec4* lp4 = reinterpret_cast<const fvec4*>(logprob);
    for (int i = tid; i < nv; i += blockDim.x) {
        ivec4 lb = yt4[i];
        ivec4 sg = sg4[i];
        fvec4 lp = lp4[i];
        #pragma unroll
        for (int k = 0; k < 4; ++k) {
            const float l = (lb[k] != IGNORE_INDEX) ? lp[k] : 0.0f;
            acc += -(wpb[sg[k]] * l);
        }
    }
    for (int i = (nv << 2) + tid; i < B; i += blockDim.x) {
        const float l = (y_true[i] != IGNORE_INDEX) ? logprob[i] : 0.0f;
        acc += -(wpb[seg[i]] * l);
    }
    #pragma unroll
    for (int off = 32; off >= 1; off >>= 1) acc += __shfl_xor(acc, off);

    __shared__ float sacc[NW];
    if (lane == 0) sacc[wave] = acc;
    __syncthreads();
    if (tid == 0) {
        float total = 0.0f;
        #pragma unroll
        for (int w = 0; w < NW; ++w) total += sacc[w];
        out[0] = total / s_num_labels;
    }
}

extern "C" void kernel_launch(void* const* d_in, const int* in_sizes, int n_in,
                              void* d_out, int out_size, void* d_ws, size_t ws_size,
                              hipStream_t stream) {
    const float* y_pred = (const float*)d_in[0];
    const int*   y_true = (const int*)d_in[1];
    const int B = in_sizes[1];
    const int C = (int)(in_sizes[0] / (size_t)in_sizes[1]);
    float* out = (float*)d_out;

    char* ws = (char*)d_ws;
    float* logprob = (float*)ws;                              // B floats
    int*   seg     = (int*)(ws + (size_t)B * sizeof(float));  // B ints

    ghmc_row_kernel<<<B, 256, 0, stream>>>(y_pred, y_true, logprob, seg, C);
    ghmc_finalize_kernel<<<1, 1024, 0, stream>>>(y_true, logprob, seg, out, B);
}